// Round 1
// 196.849 us; speedup vs baseline: 1.1589x; 1.1589x over previous
//
#include <hip/hip_runtime.h>
#include <hip/hip_fp16.h>
#include <cstdint>

typedef int v4i __attribute__((ext_vector_type(4)));

#define AS1C(p) ((const __attribute__((address_space(1))) void*)(p))
#define AS3(p)  ((__attribute__((address_space(3))) void*)(p))

// ---------------------------------------------------------------------------
// Per-row symmetric int8 quantization (unchanged — ~46 µs combined, near the
// ~40 µs HBM floor for 128+32 / 64+16 MiB of traffic).
// ---------------------------------------------------------------------------
__global__ __launch_bounds__(256) void quant_rows(const float* __restrict__ X,
                                                  int8_t* __restrict__ Q,
                                                  float* __restrict__ scales,
                                                  int K) {
    const int row = blockIdx.x;
    const float4* xv = (const float4*)(X + (size_t)row * K);
    const int nv = K >> 2;  // 1024

    float m = 0.0f;
    for (int i = threadIdx.x; i < nv; i += 256) {
        float4 v = xv[i];
        m = fmaxf(m, fabsf(v.x));
        m = fmaxf(m, fabsf(v.y));
        m = fmaxf(m, fabsf(v.z));
        m = fmaxf(m, fabsf(v.w));
    }
    for (int off = 32; off > 0; off >>= 1)
        m = fmaxf(m, __shfl_xor(m, off, 64));

    __shared__ float wmax[4];
    __shared__ float s_sc;
    const int lane = threadIdx.x & 63;
    const int wv = threadIdx.x >> 6;
    if (lane == 0) wmax[wv] = m;
    __syncthreads();
    if (threadIdx.x == 0) {
        float mm = fmaxf(fmaxf(wmax[0], wmax[1]), fmaxf(wmax[2], wmax[3]));
        float sc = mm / 127.0f;
        scales[row] = sc;
        s_sc = sc;
    }
    __syncthreads();
    const float sc = s_sc;

    char4* qv = (char4*)(Q + (size_t)row * K);
    for (int i = threadIdx.x; i < nv; i += 256) {
        float4 v = xv[i];
        char4 q;
        q.x = (signed char)(int)rintf(v.x / sc);
        q.y = (signed char)(int)rintf(v.y / sc);
        q.z = (signed char)(int)rintf(v.z / sc);
        q.w = (signed char)(int)rintf(v.w / sc);
        qv[i] = q;
    }
}

// ---------------------------------------------------------------------------
// int8 GEMM, 256x256 tile, 512 threads = 8 waves (2M x 4N), per-wave 128x64.
// K-step (BK) = 64 bytes; 4-buffer LDS ring (4 x 32 KiB = 128 KiB): while
// computing K-tile kt, stage kt+3 into the buffer freed after kt-1. Counted
// s_waitcnt vmcnt(8) ONCE per K-tile (8 loads = tiles kt+2,kt+3 stay in
// flight across raw s_barriers — no vmcnt(0) drain in the main loop).
// Two phases per K-tile: {ds_read frags | issue 2 global_load_lds | barrier |
// setprio(1) 16xMFMA setprio(0) | barrier}.
// LDS bank-conflict fix (T2): 16B chunk XOR-swizzle col ^= ((row>>1)&3)<<4
// applied as pre-swizzled GLOBAL source (global_load_lds dest must stay
// linear) + swizzled ds_read address. 16 consecutive rows -> 8 bank slots
// x 2-way = conflict-free.
// ---------------------------------------------------------------------------
__global__ __launch_bounds__(512, 2) void gemm_i8(const int8_t* __restrict__ Aq,
                                                  const int8_t* __restrict__ Bq,
                                                  const float* __restrict__ a_scale,
                                                  const float* __restrict__ w_scale,
                                                  float* __restrict__ out) {
    extern __shared__ __align__(16) int8_t smem[];  // 4 x (A 16K | B 16K)

    const int K = 4096;
    // XCD-bijective swizzle: 512 wgs, 8 XCDs, 64 contiguous wgs per XCD
    const int bid = blockIdx.x;
    const int wg  = (bid & 7) * 64 + (bid >> 3);
    const int n0 = (wg & 15) * 256;   // 16 N-blocks
    const int m0 = (wg >> 4) * 256;   // 32 M-blocks

    const int tid  = threadIdx.x;
    const int lane = tid & 63;
    const int wid  = tid >> 6;   // 0..7
    const int wm   = wid >> 2;   // 0..1 -> M offset wm*128
    const int wn   = wid & 3;    // 0..3 -> N offset wn*64

    // fragment read offsets (rows of 64 B, swizzled 16B chunks)
    const int rsel  = lane & 15;
    const int kswz  = ((lane >> 4) << 4) ^ (((rsel >> 1) & 3) << 4);
    const int abase = (wm * 128 + rsel) * 64 + kswz;
    const int bbase = (wn * 64  + rsel) * 64 + kswz;

    // staging: 512 thr x 16B = 8 KB/issue = 128 rows; 2 issues per operand tile
    const int strow = tid >> 2;                          // 0..127
    const int stswz = ((strow >> 1) & 3) << 4;
    const int stcol = ((tid & 3) << 4) ^ stswz;          // pre-swizzled source col
    const int8_t* gA = Aq + (size_t)(m0 + strow) * K + stcol;
    const int8_t* gB = Bq + (size_t)(n0 + strow) * K + stcol;
    const size_t rstep = (size_t)128 * K;
    const int ldsst = wid * 1024;                        // + lane*16 by HW

    v4i acc[8][4] = {};

    // ---- prologue: stage K-tiles 0..2 into bufs 0..2 (12 loads/thread)
#pragma unroll
    for (int kt = 0; kt < 3; ++kt) {
        int8_t* bA = smem + kt * 32768;
        int8_t* bB = bA + 16384;
        const int8_t* a = gA + kt * 64;
        const int8_t* b = gB + kt * 64;
        __builtin_amdgcn_global_load_lds(AS1C(a),         AS3(bA + ldsst),        16, 0, 0);
        __builtin_amdgcn_global_load_lds(AS1C(a + rstep), AS3(bA + 8192 + ldsst), 16, 0, 0);
        __builtin_amdgcn_global_load_lds(AS1C(b),         AS3(bB + ldsst),        16, 0, 0);
        __builtin_amdgcn_global_load_lds(AS1C(b + rstep), AS3(bB + 8192 + ldsst), 16, 0, 0);
    }
    asm volatile("s_waitcnt vmcnt(8)" ::: "memory");  // tile 0 landed; 1,2 in flight
    __builtin_amdgcn_s_barrier();

    for (int kt4 = 0; kt4 < 64; kt4 += 4) {
#pragma unroll
        for (int u = 0; u < 4; ++u) {
            const int kt = kt4 + u;
            const int8_t* bA = smem + u * 32768;          // compile-time bases
            const int8_t* bB = bA + 16384;
            int8_t* pA = smem + ((u + 3) & 3) * 32768;    // freed after kt-1
            int8_t* pB = pA + 16384;
            // clamp tail prefetch to tile 63: keeps vmcnt arithmetic uniform,
            // target buffer is dead (never read again) -> harmless re-stage
            const int ktp = (kt + 3 < 64) ? kt + 3 : 63;
            const int8_t* a = gA + (size_t)ktp * 64;
            const int8_t* b = gB + (size_t)ktp * 64;

            v4i aF[4], bF[4];
            // ---- phase 0: A-lower frags + all B frags; stage next A
#pragma unroll
            for (int mt = 0; mt < 4; ++mt)
                aF[mt] = *(const v4i*)(bA + abase + mt * 1024);
#pragma unroll
            for (int nt = 0; nt < 4; ++nt)
                bF[nt] = *(const v4i*)(bB + bbase + nt * 1024);
            __builtin_amdgcn_global_load_lds(AS1C(a),         AS3(pA + ldsst),        16, 0, 0);
            __builtin_amdgcn_global_load_lds(AS1C(a + rstep), AS3(pA + 8192 + ldsst), 16, 0, 0);
            __builtin_amdgcn_s_barrier();
            __builtin_amdgcn_s_setprio(1);
#pragma unroll
            for (int mt = 0; mt < 4; ++mt)
#pragma unroll
                for (int nt = 0; nt < 4; ++nt)
                    acc[mt][nt] = __builtin_amdgcn_mfma_i32_16x16x64_i8(
                        aF[mt], bF[nt], acc[mt][nt], 0, 0, 0);
            __builtin_amdgcn_s_setprio(0);
            __builtin_amdgcn_s_barrier();

            // ---- phase 1: A-upper frags (B frags reused); stage next B
#pragma unroll
            for (int mt = 0; mt < 4; ++mt)
                aF[mt] = *(const v4i*)(bA + abase + (mt + 4) * 1024);
            __builtin_amdgcn_global_load_lds(AS1C(b),         AS3(pB + ldsst),        16, 0, 0);
            __builtin_amdgcn_global_load_lds(AS1C(b + rstep), AS3(pB + 8192 + ldsst), 16, 0, 0);
            __builtin_amdgcn_s_barrier();
            __builtin_amdgcn_s_setprio(1);
#pragma unroll
            for (int mt = 0; mt < 4; ++mt)
#pragma unroll
                for (int nt = 0; nt < 4; ++nt)
                    acc[mt + 4][nt] = __builtin_amdgcn_mfma_i32_16x16x64_i8(
                        aF[mt], bF[nt], acc[mt + 4][nt], 0, 0, 0);
            __builtin_amdgcn_s_setprio(0);
            // retire exactly tile kt+1 (tiles kt+2, kt+3 = 8 loads stay in flight)
            asm volatile("s_waitcnt vmcnt(8)" ::: "memory");
            __builtin_amdgcn_s_barrier();
            __builtin_amdgcn_sched_barrier(0);  // no ds_read hoists above this barrier
        }
    }

    // epilogue: C/D layout col = lane&15 (N), row = (lane>>4)*4 + reg (M)
    const int r0  = (lane >> 4) << 2;
    const int col = lane & 15;
#pragma unroll
    for (int mt = 0; mt < 8; ++mt) {
        const int tbase = m0 + wm * 128 + mt * 16 + r0;
        float as[4];
#pragma unroll
        for (int r = 0; r < 4; ++r) as[r] = a_scale[tbase + r];
#pragma unroll
        for (int nt = 0; nt < 4; ++nt) {
            const int o = n0 + wn * 64 + nt * 16 + col;
            const float wsc = w_scale[o];
#pragma unroll
            for (int r = 0; r < 4; ++r) {
                float v = (float)acc[mt][nt][r] * as[r] * wsc;
                out[(size_t)(tbase + r) * 4096 + o] = __half2float(__float2half_rn(v));
            }
        }
    }
}

extern "C" void kernel_launch(void* const* d_in, const int* in_sizes, int n_in,
                              void* d_out, int out_size, void* d_ws, size_t ws_size,
                              hipStream_t stream) {
    const float* input_act = (const float*)d_in[0];  // [4,2048,4096] = [8192,4096]
    const float* weight    = (const float*)d_in[1];  // [4096,4096]
    float* out = (float*)d_out;

    const int K = 4096, O = 4096, T = 8192;

    int8_t* x_q = (int8_t*)d_ws;
    int8_t* w_q = x_q + (size_t)T * K;
    float* a_scale = (float*)(w_q + (size_t)O * K);
    float* w_scale = a_scale + T;

    static bool attr_done = false;
    if (!attr_done) {
        hipFuncSetAttribute(reinterpret_cast<const void*>(gemm_i8),
                            hipFuncAttributeMaxDynamicSharedMemorySize, 131072);
        attr_done = true;
    }

    quant_rows<<<T, 256, 0, stream>>>(input_act, x_q, a_scale, K);
    quant_rows<<<O, 256, 0, stream>>>(weight, w_q, w_scale, K);

    dim3 grid(512);  // (8192/256) x (4096/256), XCD-swizzled in-kernel
    gemm_i8<<<grid, 512, 131072, stream>>>(x_q, w_q, a_scale, w_scale, out);
}

// Round 2
// 195.749 us; speedup vs baseline: 1.1654x; 1.0056x over previous
//
#include <hip/hip_runtime.h>
#include <hip/hip_fp16.h>
#include <cstdint>

typedef int v4i __attribute__((ext_vector_type(4)));

#define AS1C(p) ((const __attribute__((address_space(1))) void*)(p))
#define AS3(p)  ((__attribute__((address_space(3))) void*)(p))

// ---------------------------------------------------------------------------
// Per-row symmetric int8 quantization (unchanged).
// ---------------------------------------------------------------------------
__global__ __launch_bounds__(256) void quant_rows(const float* __restrict__ X,
                                                  int8_t* __restrict__ Q,
                                                  float* __restrict__ scales,
                                                  int K) {
    const int row = blockIdx.x;
    const float4* xv = (const float4*)(X + (size_t)row * K);
    const int nv = K >> 2;  // 1024

    float m = 0.0f;
    for (int i = threadIdx.x; i < nv; i += 256) {
        float4 v = xv[i];
        m = fmaxf(m, fabsf(v.x));
        m = fmaxf(m, fabsf(v.y));
        m = fmaxf(m, fabsf(v.z));
        m = fmaxf(m, fabsf(v.w));
    }
    for (int off = 32; off > 0; off >>= 1)
        m = fmaxf(m, __shfl_xor(m, off, 64));

    __shared__ float wmax[4];
    __shared__ float s_sc;
    const int lane = threadIdx.x & 63;
    const int wv = threadIdx.x >> 6;
    if (lane == 0) wmax[wv] = m;
    __syncthreads();
    if (threadIdx.x == 0) {
        float mm = fmaxf(fmaxf(wmax[0], wmax[1]), fmaxf(wmax[2], wmax[3]));
        float sc = mm / 127.0f;
        scales[row] = sc;
        s_sc = sc;
    }
    __syncthreads();
    const float sc = s_sc;

    char4* qv = (char4*)(Q + (size_t)row * K);
    for (int i = threadIdx.x; i < nv; i += 256) {
        float4 v = xv[i];
        char4 q;
        q.x = (signed char)(int)rintf(v.x / sc);
        q.y = (signed char)(int)rintf(v.y / sc);
        q.z = (signed char)(int)rintf(v.z / sc);
        q.w = (signed char)(int)rintf(v.w / sc);
        qv[i] = q;
    }
}

// ---------------------------------------------------------------------------
// int8 GEMM, 256x256 tile, 512 threads = 8 waves (2M x 4N), per-wave 128x64.
// 4-buffer LDS ring (128 KiB), BK=64 B.  Cross-tile REGISTER prefetch:
// iteration kt = { vmcnt(4) [retire tile kt+1] ; s_barrier [all waves
// retired -> LDS kt+1 visible] ; ds_read tile kt+1 frags into alternate
// register set + stage tile kt+3 ; sched_barrier ; 32 MFMA on tile kt's
// fragments (already in regs -> compiler leaves next-tile ds_reads in
// flight via counted lgkmcnt) }.  LDS port time (~1024 cyc/CU/tile) hides
// under the MFMA cluster (~1306 cyc).  One barrier per K-tile.
// Race audit: (1) reads of buf[(kt+1)&3] follow {every wave's vmcnt(4),
// barrier} -> writes retired block-wide. (2) stage into buf[(kt+3)&3]
// (holds tile kt-1) follows barrier_kt; all waves' tile kt-1 reads were
// lgkm-complete before their MFMA(kt-1) which precedes barrier_kt. (3)
// tail: prefetch index clamped to 63 re-stages dead buffers; the dead
// reads at kt=63 hit buffer re-staged at kt=61, retired by vmcnt at kt=63.
// ---------------------------------------------------------------------------
__global__ __launch_bounds__(512, 2) void gemm_i8(const int8_t* __restrict__ Aq,
                                                  const int8_t* __restrict__ Bq,
                                                  const float* __restrict__ a_scale,
                                                  const float* __restrict__ w_scale,
                                                  float* __restrict__ out) {
    extern __shared__ __align__(16) int8_t smem[];  // 4 x (A 16K | B 16K)

    const int K = 4096;
    const int bid = blockIdx.x;
    const int wg  = (bid & 7) * 64 + (bid >> 3);  // bijective: 512 = 8 x 64
    const int n0 = (wg & 15) * 256;
    const int m0 = (wg >> 4) * 256;

    const int tid  = threadIdx.x;
    const int lane = tid & 63;
    const int wid  = tid >> 6;
    const int wm   = wid >> 2;
    const int wn   = wid & 3;

    // fragment read offsets (64-B rows, 16-B-chunk XOR swizzle)
    const int rsel  = lane & 15;
    const int kswz  = ((lane >> 4) << 4) ^ (((rsel >> 1) & 3) << 4);
    const int abase = (wm * 128 + rsel) * 64 + kswz;
    const int bbase = 16384 + (wn * 64 + rsel) * 64 + kswz;

    // staging: 512 thr x 16 B = 128 rows/issue; pre-swizzled global source
    const int strow = tid >> 2;
    const int stswz = ((strow >> 1) & 3) << 4;
    const int stcol = ((tid & 3) << 4) ^ stswz;
    const int8_t* gA = Aq + (size_t)(m0 + strow) * K + stcol;
    const int8_t* gB = Bq + (size_t)(n0 + strow) * K + stcol;
    const size_t rstep = (size_t)128 * K;
    const int ldsst = wid * 1024;  // + lane*16 by HW

    v4i acc[8][4] = {};
    v4i aFa[8], aFb[8], bFa[4], bFb[4];

#define STAGE(buf, kt) do {                                                          \
    int8_t* _d = smem + (buf) * 32768;                                               \
    const int8_t* _a = gA + (size_t)(kt) * 64;                                       \
    const int8_t* _b = gB + (size_t)(kt) * 64;                                       \
    __builtin_amdgcn_global_load_lds(AS1C(_a),         AS3(_d + ldsst),         16, 0, 0); \
    __builtin_amdgcn_global_load_lds(AS1C(_a + rstep), AS3(_d + 8192  + ldsst), 16, 0, 0); \
    __builtin_amdgcn_global_load_lds(AS1C(_b),         AS3(_d + 16384 + ldsst), 16, 0, 0); \
    __builtin_amdgcn_global_load_lds(AS1C(_b + rstep), AS3(_d + 24576 + ldsst), 16, 0, 0); \
  } while (0)

    // One K-tile step: consume CA/CB (tile kt), prefetch NA/NB (tile kt+1).
    // Literal array names keep every register index compile-time (no scratch).
#define KSTEP(u, CA, CB, NA, NB, kt4) do {                                           \
    const int kt  = (kt4) + (u);                                                     \
    const int8_t* bufN = smem + (((u) + 1) & 3) * 32768;                             \
    const int ktp = (kt + 3 < 64) ? (kt + 3) : 63;                                   \
    asm volatile("s_waitcnt vmcnt(4)" ::: "memory");                                 \
    __builtin_amdgcn_s_barrier();                                                    \
    _Pragma("unroll")                                                                \
    for (int mt = 0; mt < 8; ++mt)                                                   \
        NA[mt] = *(const v4i*)(bufN + abase + mt * 1024);                            \
    STAGE(((u) + 3) & 3, ktp);                                                       \
    __builtin_amdgcn_sched_barrier(0);                                               \
    __builtin_amdgcn_s_setprio(1);                                                   \
    _Pragma("unroll")                                                                \
    for (int nt = 0; nt < 4; ++nt) {                                                 \
        _Pragma("unroll")                                                            \
        for (int mt = 0; mt < 8; ++mt)                                               \
            acc[mt][nt] = __builtin_amdgcn_mfma_i32_16x16x64_i8(                     \
                CA[mt], CB[nt], acc[mt][nt], 0, 0, 0);                               \
        NB[nt] = *(const v4i*)(bufN + bbase + nt * 1024);                            \
    }                                                                                \
    __builtin_amdgcn_s_setprio(0);                                                   \
  } while (0)

    // ---- prologue: stage tiles 0..2; retire tile 0; load its fragments
    STAGE(0, 0); STAGE(1, 1); STAGE(2, 2);
    asm volatile("s_waitcnt vmcnt(8)" ::: "memory");
    __builtin_amdgcn_s_barrier();
#pragma unroll
    for (int mt = 0; mt < 8; ++mt) aFa[mt] = *(const v4i*)(smem + abase + mt * 1024);
#pragma unroll
    for (int nt = 0; nt < 4; ++nt) bFa[nt] = *(const v4i*)(smem + bbase + nt * 1024);

    for (int kt4 = 0; kt4 < 64; kt4 += 4) {
        KSTEP(0, aFa, bFa, aFb, bFb, kt4);
        KSTEP(1, aFb, bFb, aFa, bFa, kt4);
        KSTEP(2, aFa, bFa, aFb, bFb, kt4);
        KSTEP(3, aFb, bFb, aFa, bFa, kt4);
    }

    // epilogue: C/D layout col = lane&15 (N), row = (lane>>4)*4 + reg (M)
    const int r0  = (lane >> 4) << 2;
    const int col = lane & 15;
#pragma unroll
    for (int mt = 0; mt < 8; ++mt) {
        const int tbase = m0 + wm * 128 + mt * 16 + r0;
        float as[4];
#pragma unroll
        for (int r = 0; r < 4; ++r) as[r] = a_scale[tbase + r];
#pragma unroll
        for (int nt = 0; nt < 4; ++nt) {
            const int o = n0 + wn * 64 + nt * 16 + col;
            const float wsc = w_scale[o];
#pragma unroll
            for (int r = 0; r < 4; ++r) {
                float v = (float)acc[mt][nt][r] * as[r] * wsc;
                out[(size_t)(tbase + r) * 4096 + o] = __half2float(__float2half_rn(v));
            }
        }
    }
#undef KSTEP
#undef STAGE
}

extern "C" void kernel_launch(void* const* d_in, const int* in_sizes, int n_in,
                              void* d_out, int out_size, void* d_ws, size_t ws_size,
                              hipStream_t stream) {
    const float* input_act = (const float*)d_in[0];  // [4,2048,4096] = [8192,4096]
    const float* weight    = (const float*)d_in[1];  // [4096,4096]
    float* out = (float*)d_out;

    const int K = 4096, O = 4096, T = 8192;

    int8_t* x_q = (int8_t*)d_ws;
    int8_t* w_q = x_q + (size_t)T * K;
    float* a_scale = (float*)(w_q + (size_t)O * K);
    float* w_scale = a_scale + T;

    static bool attr_done = false;
    if (!attr_done) {
        hipFuncSetAttribute(reinterpret_cast<const void*>(gemm_i8),
                            hipFuncAttributeMaxDynamicSharedMemorySize, 131072);
        attr_done = true;
    }

    quant_rows<<<T, 256, 0, stream>>>(input_act, x_q, a_scale, K);
    quant_rows<<<O, 256, 0, stream>>>(weight, w_q, w_scale, K);

    dim3 grid(512);  // (8192/256) x (4096/256), XCD-swizzled in-kernel
    gemm_i8<<<grid, 512, 131072, stream>>>(x_q, w_q, a_scale, w_scale, out);
}

// Round 3
// 180.796 us; speedup vs baseline: 1.2618x; 1.0827x over previous
//
#include <hip/hip_runtime.h>
#include <hip/hip_fp16.h>
#include <cstdint>

typedef int v4i __attribute__((ext_vector_type(4)));

#define AS1C(p) ((const __attribute__((address_space(1))) void*)(p))
#define AS3(p)  ((__attribute__((address_space(3))) void*)(p))

// ---------------------------------------------------------------------------
// Per-row symmetric int8 quantization — SINGLE PASS: the row (16 KB) is held
// in registers (4 x float4/thread), so X is read from HBM exactly once.
// ---------------------------------------------------------------------------
__global__ __launch_bounds__(256) void quant_rows(const float* __restrict__ X,
                                                  int8_t* __restrict__ Q,
                                                  float* __restrict__ scales,
                                                  int K) {
    const int row = blockIdx.x;
    const float4* xv = (const float4*)(X + (size_t)row * K);

    float4 v[4];
#pragma unroll
    for (int j = 0; j < 4; ++j) v[j] = xv[threadIdx.x + (j << 8)];

    float m = 0.0f;
#pragma unroll
    for (int j = 0; j < 4; ++j) {
        m = fmaxf(m, fmaxf(fmaxf(fabsf(v[j].x), fabsf(v[j].y)),
                           fmaxf(fabsf(v[j].z), fabsf(v[j].w))));
    }
    for (int off = 32; off > 0; off >>= 1)
        m = fmaxf(m, __shfl_xor(m, off, 64));

    __shared__ float wmax[4];
    __shared__ float s_sc;
    const int lane = threadIdx.x & 63;
    const int wv = threadIdx.x >> 6;
    if (lane == 0) wmax[wv] = m;
    __syncthreads();
    if (threadIdx.x == 0) {
        float mm = fmaxf(fmaxf(wmax[0], wmax[1]), fmaxf(wmax[2], wmax[3]));
        float sc = mm / 127.0f;
        scales[row] = sc;
        s_sc = sc;
    }
    __syncthreads();
    const float sc = s_sc;

    char4* qv = (char4*)(Q + (size_t)row * K);
#pragma unroll
    for (int j = 0; j < 4; ++j) {
        char4 q;
        q.x = (signed char)(int)rintf(v[j].x / sc);  // keep division: bit-exact vs prior rounds
        q.y = (signed char)(int)rintf(v[j].y / sc);
        q.z = (signed char)(int)rintf(v[j].z / sc);
        q.w = (signed char)(int)rintf(v[j].w / sc);
        qv[threadIdx.x + (j << 8)] = q;
    }
}

// ---------------------------------------------------------------------------
// int8 GEMM, 256x256 tile, 512 threads = 8 waves (2M x 4N), per-wave 128x64.
// 4-buffer LDS ring (128 KiB), BK=64 B, register-double-buffered fragments.
// NEW: fine-grained interleave (m196 lever) — each K-tile is 4 groups of
// { 3 ds_read_b128 (next-tile frags) + 1 global_load_lds + 8 MFMA }, with
// sched_barrier(0) fences BETWEEN groups only. Both pipes stay fed: per
// group per CU, LDS ~288 cyc runs under MFMA ~326 cyc, instead of the old
// bulk alternation (reads-then-MFMA) that capped MfmaUtil at ~44%.
// Groups are mt-major (group g: acc[2g..2g+1][0..3]) so fragments read in
// group g are first consumed in group g of the NEXT tile (max slack).
// vmcnt(4) once per tile retires exactly tile kt+1's 4 staging loads
// (FIFO: 4 issues/tile, 8 in flight at tile entry). One s_barrier per tile.
// ---------------------------------------------------------------------------
__global__ __launch_bounds__(512, 2) void gemm_i8(const int8_t* __restrict__ Aq,
                                                  const int8_t* __restrict__ Bq,
                                                  const float* __restrict__ a_scale,
                                                  const float* __restrict__ w_scale,
                                                  float* __restrict__ out) {
    extern __shared__ __align__(16) int8_t smem[];  // 4 x (A 16K | B 16K)

    const int K = 4096;
    const int bid = blockIdx.x;
    const int wg  = (bid & 7) * 64 + (bid >> 3);  // bijective: 512 = 8 x 64
    const int n0 = (wg & 15) * 256;
    const int m0 = (wg >> 4) * 256;

    const int tid  = threadIdx.x;
    const int lane = tid & 63;
    const int wid  = tid >> 6;
    const int wm   = wid >> 2;
    const int wn   = wid & 3;

    // fragment read offsets (64-B rows, 16-B-chunk XOR swizzle)
    const int rsel  = lane & 15;
    const int kswz  = ((lane >> 4) << 4) ^ (((rsel >> 1) & 3) << 4);
    const int abase = (wm * 128 + rsel) * 64 + kswz;
    const int bbase = 16384 + (wn * 64 + rsel) * 64 + kswz;

    // staging: 512 thr x 16 B = 128 rows/issue; pre-swizzled global source
    const int strow = tid >> 2;
    const int stswz = ((strow >> 1) & 3) << 4;
    const int stcol = ((tid & 3) << 4) ^ stswz;
    const int8_t* gA = Aq + (size_t)(m0 + strow) * K + stcol;
    const int8_t* gB = Bq + (size_t)(n0 + strow) * K + stcol;
    const size_t rstep = (size_t)128 * K;
    const int ldsst = wid * 1024;  // + lane*16 by HW

    v4i acc[8][4] = {};
    v4i aFa[8], aFb[8], bFa[4], bFb[4];

#define STAGE(buf, kt) do {                                                          \
    int8_t* _d = smem + (buf) * 32768;                                               \
    const int8_t* _a = gA + (size_t)(kt) * 64;                                       \
    const int8_t* _b = gB + (size_t)(kt) * 64;                                       \
    __builtin_amdgcn_global_load_lds(AS1C(_a),         AS3(_d + ldsst),         16, 0, 0); \
    __builtin_amdgcn_global_load_lds(AS1C(_a + rstep), AS3(_d + 8192  + ldsst), 16, 0, 0); \
    __builtin_amdgcn_global_load_lds(AS1C(_b),         AS3(_d + 16384 + ldsst), 16, 0, 0); \
    __builtin_amdgcn_global_load_lds(AS1C(_b + rstep), AS3(_d + 24576 + ldsst), 16, 0, 0); \
  } while (0)

    // One mt-major group: 3 next-tile frag reads + 1 stage issue + 8 MFMAs.
#define GROUP(g, CA, CB, NA, NB, gsrc, goff)  do {                                   \
    NA[2*(g)]     = *(const v4i*)(bufN + abase + (2*(g))     * 1024);                \
    NA[2*(g) + 1] = *(const v4i*)(bufN + abase + (2*(g) + 1) * 1024);                \
    NB[(g)]       = *(const v4i*)(bufN + bbase + (g) * 1024);                        \
    __builtin_amdgcn_global_load_lds(AS1C(gsrc), AS3(pD + (goff) + ldsst), 16, 0, 0);\
    _Pragma("unroll")                                                                \
    for (int nt = 0; nt < 4; ++nt) {                                                 \
        acc[2*(g)][nt] = __builtin_amdgcn_mfma_i32_16x16x64_i8(                      \
            CA[2*(g)], CB[nt], acc[2*(g)][nt], 0, 0, 0);                             \
        acc[2*(g)+1][nt] = __builtin_amdgcn_mfma_i32_16x16x64_i8(                    \
            CA[2*(g)+1], CB[nt], acc[2*(g)+1][nt], 0, 0, 0);                         \
    }                                                                                \
  } while (0)

#define KSTEP(u, CA, CB, NA, NB, kt4) do {                                           \
    const int kt  = (kt4) + (u);                                                     \
    const int8_t* bufN = smem + (((u) + 1) & 3) * 32768;                             \
    int8_t* pD = smem + (((u) + 3) & 3) * 32768;                                     \
    const int ktp = (kt + 3 < 64) ? (kt + 3) : 63;                                   \
    const int8_t* _a = gA + (size_t)ktp * 64;                                        \
    const int8_t* _b = gB + (size_t)ktp * 64;                                        \
    asm volatile("s_waitcnt vmcnt(4)" ::: "memory");                                 \
    __builtin_amdgcn_s_barrier();                                                    \
    __builtin_amdgcn_s_setprio(1);                                                   \
    GROUP(0, CA, CB, NA, NB, _a,         0);                                         \
    __builtin_amdgcn_sched_barrier(0);                                               \
    GROUP(1, CA, CB, NA, NB, _a + rstep, 8192);                                      \
    __builtin_amdgcn_sched_barrier(0);                                               \
    GROUP(2, CA, CB, NA, NB, _b,         16384);                                     \
    __builtin_amdgcn_sched_barrier(0);                                               \
    GROUP(3, CA, CB, NA, NB, _b + rstep, 24576);                                     \
    __builtin_amdgcn_s_setprio(0);                                                   \
  } while (0)

    // ---- prologue: stage tiles 0..2; retire tile 0; load its fragments
    STAGE(0, 0); STAGE(1, 1); STAGE(2, 2);
    asm volatile("s_waitcnt vmcnt(8)" ::: "memory");
    __builtin_amdgcn_s_barrier();
#pragma unroll
    for (int mt = 0; mt < 8; ++mt) aFa[mt] = *(const v4i*)(smem + abase + mt * 1024);
#pragma unroll
    for (int nt = 0; nt < 4; ++nt) bFa[nt] = *(const v4i*)(smem + bbase + nt * 1024);

    for (int kt4 = 0; kt4 < 64; kt4 += 4) {
        KSTEP(0, aFa, bFa, aFb, bFb, kt4);
        KSTEP(1, aFb, bFb, aFa, bFa, kt4);
        KSTEP(2, aFa, bFa, aFb, bFb, kt4);
        KSTEP(3, aFb, bFb, aFa, bFa, kt4);
    }

    // epilogue: C/D layout col = lane&15 (N), row = (lane>>4)*4 + reg (M)
    const int r0  = (lane >> 4) << 2;
    const int col = lane & 15;
#pragma unroll
    for (int mt = 0; mt < 8; ++mt) {
        const int tbase = m0 + wm * 128 + mt * 16 + r0;
        float as[4];
#pragma unroll
        for (int r = 0; r < 4; ++r) as[r] = a_scale[tbase + r];
#pragma unroll
        for (int nt = 0; nt < 4; ++nt) {
            const int o = n0 + wn * 64 + nt * 16 + col;
            const float wsc = w_scale[o];
#pragma unroll
            for (int r = 0; r < 4; ++r) {
                float v = (float)acc[mt][nt][r] * as[r] * wsc;
                out[(size_t)(tbase + r) * 4096 + o] = __half2float(__float2half_rn(v));
            }
        }
    }
#undef KSTEP
#undef GROUP
#undef STAGE
}

extern "C" void kernel_launch(void* const* d_in, const int* in_sizes, int n_in,
                              void* d_out, int out_size, void* d_ws, size_t ws_size,
                              hipStream_t stream) {
    const float* input_act = (const float*)d_in[0];  // [4,2048,4096] = [8192,4096]
    const float* weight    = (const float*)d_in[1];  // [4096,4096]
    float* out = (float*)d_out;

    const int K = 4096, O = 4096, T = 8192;

    int8_t* x_q = (int8_t*)d_ws;
    int8_t* w_q = x_q + (size_t)T * K;
    float* a_scale = (float*)(w_q + (size_t)O * K);
    float* w_scale = a_scale + T;

    static bool attr_done = false;
    if (!attr_done) {
        hipFuncSetAttribute(reinterpret_cast<const void*>(gemm_i8),
                            hipFuncAttributeMaxDynamicSharedMemorySize, 131072);
        attr_done = true;
    }

    quant_rows<<<T, 256, 0, stream>>>(input_act, x_q, a_scale, K);
    quant_rows<<<O, 256, 0, stream>>>(weight, w_q, w_scale, K);

    dim3 grid(512);  // (8192/256) x (4096/256), XCD-swizzled in-kernel
    gemm_i8<<<grid, 512, 131072, stream>>>(x_q, w_q, a_scale, w_scale, out);
}

// Round 5
// 180.122 us; speedup vs baseline: 1.2665x; 1.0037x over previous
//
#include <hip/hip_runtime.h>
#include <hip/hip_fp16.h>
#include <cstdint>

typedef int v4i __attribute__((ext_vector_type(4)));

#define AS1C(p) ((const __attribute__((address_space(1))) void*)(p))
#define AS3(p)  ((__attribute__((address_space(3))) void*)(p))

// ---------------------------------------------------------------------------
// Per-row symmetric int8 quantization — single pass, row held in registers.
// ---------------------------------------------------------------------------
__global__ __launch_bounds__(256) void quant_rows(const float* __restrict__ X,
                                                  int8_t* __restrict__ Q,
                                                  float* __restrict__ scales,
                                                  int K) {
    const int row = blockIdx.x;
    const float4* xv = (const float4*)(X + (size_t)row * K);

    float4 v[4];
#pragma unroll
    for (int j = 0; j < 4; ++j) v[j] = xv[threadIdx.x + (j << 8)];

    float m = 0.0f;
#pragma unroll
    for (int j = 0; j < 4; ++j) {
        m = fmaxf(m, fmaxf(fmaxf(fabsf(v[j].x), fabsf(v[j].y)),
                           fmaxf(fabsf(v[j].z), fabsf(v[j].w))));
    }
    for (int off = 32; off > 0; off >>= 1)
        m = fmaxf(m, __shfl_xor(m, off, 64));

    __shared__ float wmax[4];
    __shared__ float s_sc;
    const int lane = threadIdx.x & 63;
    const int wv = threadIdx.x >> 6;
    if (lane == 0) wmax[wv] = m;
    __syncthreads();
    if (threadIdx.x == 0) {
        float mm = fmaxf(fmaxf(wmax[0], wmax[1]), fmaxf(wmax[2], wmax[3]));
        float sc = mm / 127.0f;
        scales[row] = sc;
        s_sc = sc;
    }
    __syncthreads();
    const float sc = s_sc;

    char4* qv = (char4*)(Q + (size_t)row * K);
#pragma unroll
    for (int j = 0; j < 4; ++j) {
        char4 q;
        q.x = (signed char)(int)rintf(v[j].x / sc);
        q.y = (signed char)(int)rintf(v[j].y / sc);
        q.z = (signed char)(int)rintf(v[j].z / sc);
        q.w = (signed char)(int)rintf(v[j].w / sc);
        qv[threadIdx.x + (j << 8)] = q;
    }
}

// ---------------------------------------------------------------------------
// int8 GEMM, 256x256 tile, 512 threads = 8 waves (2M x 4N), per-wave 128x64.
// 4-buffer LDS ring (128 KiB), BK=64 B, register-double-buffered fragments,
// 4 groups/tile of { 3 ds_read (next tile) + 1 global_load_lds + 8 MFMA }.
// T5 scoping: setprio(1) wraps ONLY each 8-MFMA cluster — reads and staging
// run at prio 0. With 2 waves/SIMD in lockstep, this gives the CU scheduler
// the role-split signal: a wave in its MFMA burst out-prioritizes its
// sibling still issuing ds_reads, the two drift into anti-phase, and the
// MFMA-pipe time covers LDS-port time instead of serializing with it.
// (Round-3 had prio(1) spanning the whole tile => no arbitration signal =>
// pipes alternated: measured 2390 cyc/tile = 1306 MFMA + ~1100 LDS serial.)
// vmcnt(4) once per tile retires exactly tile kt+1's staging; one s_barrier
// per tile; sched_barrier(0) fences keep read/MFMA clusters intact.
// ---------------------------------------------------------------------------
__global__ __launch_bounds__(512, 2) void gemm_i8(const int8_t* __restrict__ Aq,
                                                  const int8_t* __restrict__ Bq,
                                                  const float* __restrict__ a_scale,
                                                  const float* __restrict__ w_scale,
                                                  float* __restrict__ out) {
    extern __shared__ __align__(16) int8_t smem[];  // 4 x (A 16K | B 16K)

    const int K = 4096;
    const int bid = blockIdx.x;
    const int wg  = (bid & 7) * 64 + (bid >> 3);  // bijective: 512 = 8 x 64
    const int n0 = (wg & 15) * 256;
    const int m0 = (wg >> 4) * 256;

    const int tid  = threadIdx.x;
    const int lane = tid & 63;
    const int wid  = tid >> 6;
    const int wm   = wid >> 2;
    const int wn   = wid & 3;

    // fragment read offsets (64-B rows, 16-B-chunk XOR swizzle)
    const int rsel  = lane & 15;
    const int kswz  = ((lane >> 4) << 4) ^ (((rsel >> 1) & 3) << 4);
    const int abase = (wm * 128 + rsel) * 64 + kswz;
    const int bbase = 16384 + (wn * 64 + rsel) * 64 + kswz;

    // staging: 512 thr x 16 B = 128 rows/issue; pre-swizzled global source
    const int strow = tid >> 2;
    const int stswz = ((strow >> 1) & 3) << 4;
    const int stcol = ((tid & 3) << 4) ^ stswz;
    const int8_t* gA = Aq + (size_t)(m0 + strow) * K + stcol;
    const int8_t* gB = Bq + (size_t)(n0 + strow) * K + stcol;
    const size_t rstep = (size_t)128 * K;
    const int ldsst = wid * 1024;  // + lane*16 by HW

    v4i acc[8][4] = {};
    v4i aFa[8], aFb[8], bFa[4], bFb[4];

#define STAGE(buf, kt) do {                                                          \
    int8_t* _d = smem + (buf) * 32768;                                               \
    const int8_t* _a = gA + (size_t)(kt) * 64;                                       \
    const int8_t* _b = gB + (size_t)(kt) * 64;                                       \
    __builtin_amdgcn_global_load_lds(AS1C(_a),         AS3(_d + ldsst),         16, 0, 0); \
    __builtin_amdgcn_global_load_lds(AS1C(_a + rstep), AS3(_d + 8192  + ldsst), 16, 0, 0); \
    __builtin_amdgcn_global_load_lds(AS1C(_b),         AS3(_d + 16384 + ldsst), 16, 0, 0); \
    __builtin_amdgcn_global_load_lds(AS1C(_b + rstep), AS3(_d + 24576 + ldsst), 16, 0, 0); \
  } while (0)

    // One mt-major group: {reads + stage issue}@prio0, then 8 MFMAs @prio1.
#define GROUP(g, CA, CB, NA, NB, gsrc, goff)  do {                                   \
    NA[2*(g)]     = *(const v4i*)(bufN + abase + (2*(g))     * 1024);                \
    NA[2*(g) + 1] = *(const v4i*)(bufN + abase + (2*(g) + 1) * 1024);                \
    NB[(g)]       = *(const v4i*)(bufN + bbase + (g) * 1024);                        \
    __builtin_amdgcn_global_load_lds(AS1C(gsrc), AS3(pD + (goff) + ldsst), 16, 0, 0);\
    __builtin_amdgcn_sched_barrier(0);                                               \
    __builtin_amdgcn_s_setprio(1);                                                   \
    _Pragma("unroll")                                                                \
    for (int nt = 0; nt < 4; ++nt) {                                                 \
        acc[2*(g)][nt] = __builtin_amdgcn_mfma_i32_16x16x64_i8(                      \
            CA[2*(g)], CB[nt], acc[2*(g)][nt], 0, 0, 0);                             \
        acc[2*(g)+1][nt] = __builtin_amdgcn_mfma_i32_16x16x64_i8(                    \
            CA[2*(g)+1], CB[nt], acc[2*(g)+1][nt], 0, 0, 0);                         \
    }                                                                                \
    __builtin_amdgcn_s_setprio(0);                                                   \
    __builtin_amdgcn_sched_barrier(0);                                               \
  } while (0)

#define KSTEP(u, CA, CB, NA, NB, kt4) do {                                           \
    const int kt  = (kt4) + (u);                                                     \
    const int8_t* bufN = smem + (((u) + 1) & 3) * 32768;                             \
    int8_t* pD = smem + (((u) + 3) & 3) * 32768;                                     \
    const int ktp = (kt + 3 < 64) ? (kt + 3) : 63;                                   \
    const int8_t* _a = gA + (size_t)ktp * 64;                                        \
    const int8_t* _b = gB + (size_t)ktp * 64;                                        \
    asm volatile("s_waitcnt vmcnt(4)" ::: "memory");                                 \
    __builtin_amdgcn_s_barrier();                                                    \
    GROUP(0, CA, CB, NA, NB, _a,         0);                                         \
    GROUP(1, CA, CB, NA, NB, _a + rstep, 8192);                                      \
    GROUP(2, CA, CB, NA, NB, _b,         16384);                                     \
    GROUP(3, CA, CB, NA, NB, _b + rstep, 24576);                                     \
  } while (0)

    // ---- prologue: stage tiles 0..2; retire tile 0; load its fragments
    STAGE(0, 0); STAGE(1, 1); STAGE(2, 2);
    asm volatile("s_waitcnt vmcnt(8)" ::: "memory");
    __builtin_amdgcn_s_barrier();
#pragma unroll
    for (int mt = 0; mt < 8; ++mt) aFa[mt] = *(const v4i*)(smem + abase + mt * 1024);
#pragma unroll
    for (int nt = 0; nt < 4; ++nt) bFa[nt] = *(const v4i*)(smem + bbase + nt * 1024);

    for (int kt4 = 0; kt4 < 64; kt4 += 4) {
        KSTEP(0, aFa, bFa, aFb, bFb, kt4);
        KSTEP(1, aFb, bFb, aFa, bFa, kt4);
        KSTEP(2, aFa, bFa, aFb, bFb, kt4);
        KSTEP(3, aFb, bFb, aFa, bFa, kt4);
    }

    // epilogue: C/D layout col = lane&15 (N), row = (lane>>4)*4 + reg (M)
    const int r0  = (lane >> 4) << 2;
    const int col = lane & 15;
#pragma unroll
    for (int mt = 0; mt < 8; ++mt) {
        const int tbase = m0 + wm * 128 + mt * 16 + r0;
        float as[4];
#pragma unroll
        for (int r = 0; r < 4; ++r) as[r] = a_scale[tbase + r];
#pragma unroll
        for (int nt = 0; nt < 4; ++nt) {
            const int o = n0 + wn * 64 + nt * 16 + col;
            const float wsc = w_scale[o];
#pragma unroll
            for (int r = 0; r < 4; ++r) {
                float v = (float)acc[mt][nt][r] * as[r] * wsc;
                out[(size_t)(tbase + r) * 4096 + o] = __half2float(__float2half_rn(v));
            }
        }
    }
#undef KSTEP
#undef GROUP
#undef STAGE
}

extern "C" void kernel_launch(void* const* d_in, const int* in_sizes, int n_in,
                              void* d_out, int out_size, void* d_ws, size_t ws_size,
                              hipStream_t stream) {
    const float* input_act = (const float*)d_in[0];  // [4,2048,4096] = [8192,4096]
    const float* weight    = (const float*)d_in[1];  // [4096,4096]
    float* out = (float*)d_out;

    const int K = 4096, O = 4096, T = 8192;

    int8_t* x_q = (int8_t*)d_ws;
    int8_t* w_q = x_q + (size_t)T * K;
    float* a_scale = (float*)(w_q + (size_t)O * K);
    float* w_scale = a_scale + T;

    static bool attr_done = false;
    if (!attr_done) {
        hipFuncSetAttribute(reinterpret_cast<const void*>(gemm_i8),
                            hipFuncAttributeMaxDynamicSharedMemorySize, 131072);
        attr_done = true;
    }

    quant_rows<<<T, 256, 0, stream>>>(input_act, x_q, a_scale, K);
    quant_rows<<<O, 256, 0, stream>>>(weight, w_q, w_scale, K);

    dim3 grid(512);  // (8192/256) x (4096/256), XCD-swizzled in-kernel
    gemm_i8<<<grid, 512, 131072, stream>>>(x_q, w_q, a_scale, w_scale, out);
}